// Round 10
// baseline (179.783 us; speedup 1.0000x reference)
//
#include <hip/hip_runtime.h>

#define IH 512
#define IW 512
#define OH 510
#define OW 510
#define NB 32
#define KO 16
#define RB 34            // output rows per band (15 * 34 = 510)
#define LR (RB + 2)      // 36 staged input rows
#define NBAND (OH / RB)  // 15
#define OHW (OH * OW)

typedef float f32x4 __attribute__((ext_vector_type(4)));
typedef float f32x2 __attribute__((ext_vector_type(2)));

// R10: LDS-decoupled producer + fill-like per-wave store streams.
// Block (512 thr, 8 waves) = (image n, 34-row band): stage 36 x-rows (72KB)
// to LDS once; wave w then computes planes {2w, 2w+1} for the whole band,
// writing each plane as ONE monotonically ascending contiguous stream of
// lane-contiguous f32x2 stores (full cacheline coverage; R7 proved strided
// lanes are fatal). Per CU: 32 ascending streams with stores spread over the
// wave's whole lifetime (fill-kernel-like), vs R9's 256 scattered bursts
// gated by load->FMA->store chains. x is read from HBM exactly once (35 MB).
__global__ __launch_bounds__(512, 4) void conv3x3_k16_kernel(
    const float* __restrict__ x,
    const float* __restrict__ k,
    float* __restrict__ out)
{
    __shared__ float lds[LR * IW + 4];   // +4 pad

    const int bid  = blockIdx.x;
    const int band = bid % NBAND;
    const int n    = bid / NBAND;
    const int i0   = band * RB;

    const int t = threadIdx.x;

    // ---- stage 36 rows x 512 cols, coalesced float4, HBM-read-once ----
    const float* xb = x + ((size_t)n * IH + i0) * IW;
#pragma unroll
    for (int c = 0; c < 9; ++c) {
        const int idx = c * 2048 + 4 * t;
        *reinterpret_cast<f32x4*>(&lds[idx]) =
            *reinterpret_cast<const f32x4*>(xb + idx);
    }
    __syncthreads();

    // ---- per-wave: two planes, full band, independent (no more syncs) ----
    const int w    = t >> 6;     // wave 0..7
    const int lane = t & 63;
    const int o0   = 2 * w;

    float wgt[2][9];
#pragma unroll
    for (int q = 0; q < 9; ++q) {
        wgt[0][q] = k[o0 * 9 + q];
        wgt[1][q] = k[o0 * 9 + 9 + q];
    }

    // 4 column groups: group g owns out cols {128g + 2*lane, +1}; its taps
    // need x cols [128g + 2*lane, +3]. Rolling 3-row register window.
    float W[4][3][4];
#pragma unroll
    for (int s = 0; s < 2; ++s)
#pragma unroll
        for (int g = 0; g < 4; ++g) {
            const int base = s * IW + g * 128 + 2 * lane;
            const f32x2 u0 = *reinterpret_cast<const f32x2*>(&lds[base]);
            const f32x2 u1 = *reinterpret_cast<const f32x2*>(&lds[base + 2]);
            W[g][s][0] = u0[0]; W[g][s][1] = u0[1];
            W[g][s][2] = u1[0]; W[g][s][3] = u1[1];
        }

    float* op0 = out + ((size_t)(n * KO + o0) * OH + i0) * OW;
    float* op1 = op0 + (size_t)OHW;

#pragma unroll
    for (int r = 0; r < RB; ++r) {
        const int s2  = (r + 2) % 3;   // compile-time (full unroll)
        const int st0 = r % 3;
        const int st1 = (r + 1) % 3;

        // load x row r+2 into window slot s2
#pragma unroll
        for (int g = 0; g < 4; ++g) {
            const int base = (r + 2) * IW + g * 128 + 2 * lane;
            const f32x2 u0 = *reinterpret_cast<const f32x2*>(&lds[base]);
            const f32x2 u1 = *reinterpret_cast<const f32x2*>(&lds[base + 2]);
            W[g][s2][0] = u0[0]; W[g][s2][1] = u0[1];
            W[g][s2][2] = u1[0]; W[g][s2][3] = u1[1];
        }

        const int rowoff = r * OW;
#pragma unroll
        for (int g = 0; g < 4; ++g) {
            float a00 = 0.f, a01 = 0.f, a10 = 0.f, a11 = 0.f;
#pragma unroll
            for (int tc = 0; tc < 3; ++tc) {
                a00 = fmaf(W[g][st0][tc],     wgt[0][tc],     a00);
                a00 = fmaf(W[g][st1][tc],     wgt[0][3 + tc], a00);
                a00 = fmaf(W[g][s2 ][tc],     wgt[0][6 + tc], a00);
                a01 = fmaf(W[g][st0][tc + 1], wgt[0][tc],     a01);
                a01 = fmaf(W[g][st1][tc + 1], wgt[0][3 + tc], a01);
                a01 = fmaf(W[g][s2 ][tc + 1], wgt[0][6 + tc], a01);
                a10 = fmaf(W[g][st0][tc],     wgt[1][tc],     a10);
                a10 = fmaf(W[g][st1][tc],     wgt[1][3 + tc], a10);
                a10 = fmaf(W[g][s2 ][tc],     wgt[1][6 + tc], a10);
                a11 = fmaf(W[g][st0][tc + 1], wgt[1][tc],     a11);
                a11 = fmaf(W[g][st1][tc + 1], wgt[1][3 + tc], a11);
                a11 = fmaf(W[g][s2 ][tc + 1], wgt[1][6 + tc], a11);
            }
            const int coff = rowoff + g * 128 + 2 * lane;
            if (g < 3 || lane < 63) {   // g3 lane63 would be cols 510,511
                f32x2 v0; v0[0] = a00; v0[1] = a01;
                __builtin_nontemporal_store(v0,
                    reinterpret_cast<f32x2*>(op0 + coff));
                f32x2 v1; v1[0] = a10; v1[1] = a11;
                __builtin_nontemporal_store(v1,
                    reinterpret_cast<f32x2*>(op1 + coff));
            }
        }
    }
}

extern "C" void kernel_launch(void* const* d_in, const int* in_sizes, int n_in,
                              void* d_out, int out_size, void* d_ws, size_t ws_size,
                              hipStream_t stream) {
    const float* x   = (const float*)d_in[0];
    const float* ker = (const float*)d_in[1];
    float* out       = (float*)d_out;

    dim3 grid(NB * NBAND);   // 480 blocks: (image, band) — single generation
    dim3 block(512);
    conv3x3_k16_kernel<<<grid, block, 0, stream>>>(x, ker, out);
}